// Round 16
// baseline (113.468 us; speedup 1.0000x reference)
//
#include <hip/hip_runtime.h>

typedef __attribute__((ext_vector_type(4))) float f32x4;
typedef __attribute__((ext_vector_type(8))) short s16x8;

#define NG     8000
#define NRPT   8000
#define NSKIN  128
#define NT     64          // r-cols per block
#define KCH    800
#define NKC    10
#define NTILES 25          // 32-k tiles per chunk
#define TPB    256
#define WS_TILE_B 16384    // per 32k-tile: Ar|Ai planes, 8KB each, fragment-ordered
#define WS_NEED   ((size_t)NKC*NTILES*WS_TILE_B)   // 4,096,000 B

__device__ __forceinline__ float sin_rev(float u){ float r; asm("v_sin_f32 %0, %1" : "=v"(r) : "v"(u)); return r; }
__device__ __forceinline__ float cos_rev(float u){ float r; asm("v_cos_f32 %0, %1" : "=v"(r) : "v"(u)); return r; }
__device__ __forceinline__ unsigned int cvt_pk(float lo, float hi){
    unsigned int r; asm("v_cvt_pk_bf16_f32 %0, %1, %2" : "=v"(r) : "v"(lo), "v"(hi)); return r;
}
__device__ __forceinline__ s16x8 pack_u4(unsigned int a, unsigned int b, unsigned int c, unsigned int d){
    union { s16x8 v; uint4 u; } r;
    r.u = make_uint4(a,b,c,d);
    return r.v;
}
__device__ __forceinline__ s16x8 pack8(float4 v0, float4 v1){
    return pack_u4(cvt_pk(v0.x,v0.y), cvt_pk(v0.z,v0.w), cvt_pk(v1.x,v1.y), cvt_pk(v1.z,v1.w));
}

// ---- pre-pass: cg fp32 -> bf16 in MFMA-fragment order ----
__global__ __launch_bounds__(256) void bloch_prepass(
    const float* __restrict__ cgr, const float* __restrict__ cgi,
    char* __restrict__ ws)
{
    int gid = blockIdx.x*256 + threadIdx.x;
    if (gid >= NKC*NTILES*2*8*64) return;
    int lane  = gid & 63;
    int rb8   = (gid >> 6) & 7;
    int plane = (gid >> 9) & 1;
    int tile  = gid >> 10;
    int row   = rb8*16 + (lane & 15);
    int k     = tile*32 + (lane >> 4)*8;
    const float* src = plane ? cgi : cgr;
    const float4 v0 = *(const float4*)&src[(size_t)row*NG + k];
    const float4 v1 = *(const float4*)&src[(size_t)row*NG + k + 4];
    uint4 p;
    p.x = cvt_pk(v0.x, v0.y); p.y = cvt_pk(v0.z, v0.w);
    p.z = cvt_pk(v1.x, v1.y); p.w = cvt_pk(v1.z, v1.w);
    *(uint4*)(ws + (size_t)gid*16) = p;
}

// Barrier-free K-loop: each lane generates its OWN B-fragments in registers
// (B-frag = one r-column x 8 consecutive G = one phase run). No LDS staging,
// no __syncthreads in the loop -> waves are independent streams; MFMA/VALU
// overlap via wave co-scheduling (m114). (256,3): cap ~170 VGPR, 12 waves/CU.
template<bool PRE>
__global__ __launch_bounds__(TPB, 3) void bloch15(
    const float* __restrict__ Amat, const float* __restrict__ kgrid,
    const float* __restrict__ cgr,  const float* __restrict__ cgi,
    const float* __restrict__ rpts, const char* __restrict__ ws,
    float* __restrict__ out, int out_size)
{
    __shared__ float fracS[NT][4];
    __shared__ float2 ekrS[NT][4];
    __shared__ float invAS[9];
    __shared__ float scaleS;

    const int tid = threadIdx.x;
    const int bid = blockIdx.x;
    // kc-partners of an output tile are 128 apart in bid -> same bid%8 -> same XCD
    const int kc  = bid >> 7;           // 0..9
    const int rb  = bid & 127;          // 0..127
    if (rb >= 125) return;              // uniform early-out
    const int r_base = rb * NT;

    if (tid == 0) {
        float a00=Amat[0],a01=Amat[1],a02=Amat[2];
        float a10=Amat[3],a11=Amat[4],a12=Amat[5];
        float a20=Amat[6],a21=Amat[7],a22=Amat[8];
        float c00 =  (a11*a22 - a12*a21);
        float c01 = -(a10*a22 - a12*a20);
        float c02 =  (a10*a21 - a11*a20);
        float det = a00*c00 + a01*c01 + a02*c02;
        float id  = 1.0f/det;
        invAS[0] =  c00*id;
        invAS[1] = -(a01*a22 - a02*a21)*id;
        invAS[2] =  (a01*a12 - a02*a11)*id;
        invAS[3] =  c01*id;
        invAS[4] =  (a00*a22 - a02*a20)*id;
        invAS[5] = -(a00*a12 - a02*a10)*id;
        invAS[6] =  c02*id;
        invAS[7] = -(a00*a21 - a01*a20)*id;
        invAS[8] =  (a00*a11 - a01*a10)*id;
        scaleS   = rsqrtf(fabsf(det));
    }
    __syncthreads();

    if (tid < NT) {
        int rg = r_base + tid;
        float r0 = rpts[rg*3+0], r1 = rpts[rg*3+1], r2 = rpts[rg*3+2];
        fracS[tid][0] = r0*invAS[0] + r1*invAS[3] + r2*invAS[6];
        fracS[tid][1] = r0*invAS[1] + r1*invAS[4] + r2*invAS[7];
        fracS[tid][2] = r0*invAS[2] + r1*invAS[5] + r2*invAS[8];
    }
    __syncthreads();

    f32x4 accRe[4][2], accIm[4][2];
    #pragma unroll
    for (int mi = 0; mi < 4; ++mi)
        #pragma unroll
        for (int ni = 0; ni < 2; ++ni) {
            accRe[mi][ni] = (f32x4){0.f,0.f,0.f,0.f};
            accIm[mi][ni] = (f32x4){0.f,0.f,0.f,0.f};
        }

    const int lane = tid & 63;
    const int wid  = tid >> 6;     // 0..3
    const int wm   = wid >> 1;     // M half (64 rows)
    const int wn   = wid & 1;      // N half (32 cols)
    const int frow = lane & 15;
    const int kq   = lane >> 4;

    // per-lane B columns (2): col[ni] = wn*32 + ni*16 + frow
    float f0c[2], f1c[2], f2c[2], w1cc[2], w1sc[2], wdcc[2], wdsc[2];
    #pragma unroll
    for (int ni = 0; ni < 2; ++ni) {
        int col = wn*32 + ni*16 + frow;
        f0c[ni] = fracS[col][0]; f1c[ni] = fracS[col][1]; f2c[ni] = fracS[col][2];
        float u1 = f2c[ni] - floorf(f2c[ni]);
        w1cc[ni] = cos_rev(u1); w1sc[ni] = sin_rev(u1);          // e^{2pi i f2}
        float yd = -20.0f * f2c[ni]; yd -= floorf(yd);
        float wc_ = cos_rev(yd), ws_ = sin_rev(yd);
        wdcc[ni] = w1cc[ni]*wc_ - w1sc[ni]*ws_;                  // w1 * e^{-2pi i 20 f2}
        wdsc[ni] = w1cc[ni]*ws_ + w1sc[ni]*wc_;
    }

    s16x8 arfP[4], aifP[4];    // A fragments (current tile)
    auto loadA = [&](int t){
        if (PRE) {
            const char* tb = ws + (size_t)(kc*NTILES + t)*WS_TILE_B + lane*16;
            #pragma unroll
            for (int mi = 0; mi < 4; ++mi) {
                arfP[mi] = *(const s16x8*)(tb +        (wm*4 + mi)*1024);
                aifP[mi] = *(const s16x8*)(tb + 8192 + (wm*4 + mi)*1024);
            }
        } else {
            #pragma unroll
            for (int mi = 0; mi < 4; ++mi) {
                int row = wm*64 + mi*16 + frow;
                int k   = kc*KCH + t*32 + kq*8;
                const float* pr_ = &cgr[(size_t)row*NG + k];
                const float* pi_ = &cgi[(size_t)row*NG + k];
                arfP[mi] = pack8(*(const float4*)pr_, *(const float4*)(pr_+4));
                aifP[mi] = pack8(*(const float4*)pi_, *(const float4*)(pi_+4));
            }
        }
    };

    loadA(0);

    #pragma unroll 1
    for (int t = 0; t < NTILES; ++t) {
        // ---- generate this lane's 2 B-fragments in registers (8-run each) ----
        s16x8 bcf[2], bsf[2], bsnf[2];
        const int g0 = kc*KCH + t*32 + kq*8;
        const int i12  = (g0 * 3277) >> 16;          // g0/20 (exact, g0<16000)
        const int i3_0 = g0 - i12*20;
        const int i1a  = (i12 * 3277) >> 16; const int i2a = i12 - i1a*20;
        const int i12b = i12 + 1;
        const int i1b  = (i12b * 3277) >> 16; const int i2b = i12b - i1b*20;
        const float m1a = (float)(i1a - (i1a >= 10 ? 20 : 0));
        const float m2a = (float)(i2a - (i2a >= 10 ? 20 : 0));
        const float dm1 = (float)((i1b - (i1b >= 10 ? 20 : 0))) - m1a;
        const float dm2 = (float)((i2b - (i2b >= 10 ? 20 : 0))) - m2a;
        const float m30 = (float)(i3_0 - (i3_0 >= 10 ? 20 : 0));
        #pragma unroll
        for (int ni = 0; ni < 2; ++ni) {
            float y0 = m1a*f0c[ni] + m2a*f1c[ni] + m30*f2c[ni]; y0 -= floorf(y0);
            float cc = cos_rev(y0), cs = sin_rev(y0);
            float rd = dm1*f0c[ni] + dm2*f1c[ni]; rd -= floorf(rd);
            float rc = cos_rev(rd), rs = sin_rev(rd);
            float wXc = w1cc[ni]*rc - w1sc[ni]*rs;     // i12-cross multiplier
            float wXs = w1cc[ni]*rs + w1sc[ni]*rc;
            float bcv[8], bsv[8];
            bcv[0] = cc; bsv[0] = cs;
            #pragma unroll
            for (int j = 1; j < 8; ++j) {
                bool cB = (i3_0 == 20 - j);            // i12 boundary at step j
                bool cD = (i3_0 == 10 - j);            // m3 decade jump at step j
                float mc = cB ? wXc : (cD ? wdcc[ni] : w1cc[ni]);
                float ms = cB ? wXs : (cD ? wdsc[ni] : w1sc[ni]);
                float nc = cc*mc - cs*ms;
                float ns = cc*ms + cs*mc;
                cc = nc; cs = ns;
                bcv[j] = cc; bsv[j] = cs;
            }
            bcf[ni] = pack_u4(cvt_pk(bcv[0],bcv[1]), cvt_pk(bcv[2],bcv[3]),
                              cvt_pk(bcv[4],bcv[5]), cvt_pk(bcv[6],bcv[7]));
            bsf[ni] = pack_u4(cvt_pk(bsv[0],bsv[1]), cvt_pk(bsv[2],bsv[3]),
                              cvt_pk(bsv[4],bsv[5]), cvt_pk(bsv[6],bsv[7]));
            bsnf[ni] = pack_u4(cvt_pk(-bsv[0],-bsv[1]), cvt_pk(-bsv[2],-bsv[3]),
                               cvt_pk(-bsv[4],-bsv[5]), cvt_pk(-bsv[6],-bsv[7]));
        }

        // ---- 32 MFMAs (A waited on here via auto s_waitcnt) ----
        __builtin_amdgcn_s_setprio(1);
        #pragma unroll
        for (int mi = 0; mi < 4; ++mi)
            #pragma unroll
            for (int ni = 0; ni < 2; ++ni) {
                // Re += Ar*c + Ai*(-s) ; Im += Ar*s + Ai*c
                accRe[mi][ni] = __builtin_amdgcn_mfma_f32_16x16x32_bf16(arfP[mi], bcf[ni],  accRe[mi][ni], 0, 0, 0);
                accRe[mi][ni] = __builtin_amdgcn_mfma_f32_16x16x32_bf16(aifP[mi], bsnf[ni], accRe[mi][ni], 0, 0, 0);
                accIm[mi][ni] = __builtin_amdgcn_mfma_f32_16x16x32_bf16(arfP[mi], bsf[ni],  accIm[mi][ni], 0, 0, 0);
                accIm[mi][ni] = __builtin_amdgcn_mfma_f32_16x16x32_bf16(aifP[mi], bcf[ni],  accIm[mi][ni], 0, 0, 0);
            }
        __builtin_amdgcn_s_setprio(0);

        if (t + 1 < NTILES) loadA(t + 1);   // issue next A; phase-gen of t+1 hides it
    }

    // ---- e^{i k.r} table; one sincos per thread ----
    {
        int col = tid >> 2, kidx = tid & 3;
        int rg = r_base + col;
        float r0 = rpts[rg*3+0], r1 = rpts[rg*3+1], r2 = rpts[rg*3+2];
        float ang = (r0*kgrid[kidx*3+0] + r1*kgrid[kidx*3+1] + r2*kgrid[kidx*3+2])
                    * 0.15915494309189535f;
        float u = ang - floorf(ang);
        ekrS[col][kidx] = make_float2(cos_rev(u), sin_rev(u));
    }
    __syncthreads();

    // ---- epilogue: rotate by exp(i k.r), scale, atomic-accumulate ----
    const bool write_imag = (out_size >= 2*NSKIN*NRPT);
    const float scale = scaleS;
    #pragma unroll
    for (int mi = 0; mi < 4; ++mi) {
        const int m0 = wm*64 + mi*16;
        const int kidx = (m0 >> 4) & 3;
        #pragma unroll
        for (int ni = 0; ni < 2; ++ni) {
            int col = wn*32 + ni*16 + frow;
            int rg = r_base + col;
            float2 e = ekrS[col][kidx];
            float ck = e.x, sk = e.y;
            #pragma unroll
            for (int v = 0; v < 4; ++v) {
                int sg = m0 + kq*4 + v;
                float re = accRe[mi][ni][v];
                float im = accIm[mi][ni][v];
                float orr = (re*ck - im*sk) * scale;
                size_t lin = (size_t)sg * NRPT + rg;
                if (write_imag) {
                    float oi = (re*sk + im*ck) * scale;
                    size_t idx2 = lin * 2;
                    if (idx2 + 1 < (size_t)out_size) {
                        atomicAdd(&out[idx2],   orr);
                        atomicAdd(&out[idx2+1], oi);
                    }
                } else {
                    atomicAdd(&out[lin], orr);
                }
            }
        }
    }
}

extern "C" void kernel_launch(void* const* d_in, const int* in_sizes, int n_in,
                              void* d_out, int out_size, void* d_ws, size_t ws_size,
                              hipStream_t stream) {
    const float* Amat  = (const float*)d_in[0];
    const float* kgrid = (const float*)d_in[1];
    const float* cgr   = (const float*)d_in[2];
    const float* cgi   = (const float*)d_in[3];
    const float* rpts  = (const float*)d_in[4];
    float* out = (float*)d_out;

    hipMemsetAsync(d_out, 0, (size_t)out_size * sizeof(float), stream);

    const bool use_pre = (ws_size >= WS_NEED);
    dim3 grid(NKC * 128);   // kc = bid>>7, rb = bid&127 (3 dead bids per kc)
    if (use_pre) {
        bloch_prepass<<<dim3(NKC*NTILES*2*8*64/256), 256, 0, stream>>>(cgr, cgi, (char*)d_ws);
        bloch15<true><<<grid, TPB, 0, stream>>>(Amat, kgrid, cgr, cgi, rpts,
                                                (const char*)d_ws, out, out_size);
    } else {
        bloch15<false><<<grid, TPB, 0, stream>>>(Amat, kgrid, cgr, cgi, rpts,
                                                 nullptr, out, out_size);
    }
}

// Round 17
// 94.420 us; speedup vs baseline: 1.2017x; 1.2017x over previous
//
#include <hip/hip_runtime.h>

typedef __attribute__((ext_vector_type(16))) float f32x16;
typedef __attribute__((ext_vector_type(8))) short s16x8;

#define NG     8000
#define NRPT   8000
#define NSKIN  128
#define NT     64          // r-cols per block
#define KCH    800
#define NKC    10
#define NTILES 25          // 32-k tiles per chunk
#define NROUND 10          // 80-g staging rounds per chunk
#define NSLOT  6           // ring slots (192 g)
#define TPB    256
#define WS_TILE_B 16384    // per 32k-tile: Ar|Ai planes, 8KB each, 32x32-fragment-ordered
#define WS_NEED   ((size_t)NKC*NTILES*WS_TILE_B)   // 4,096,000 B

__device__ __forceinline__ float sin_rev(float u){ float r; asm("v_sin_f32 %0, %1" : "=v"(r) : "v"(u)); return r; }
__device__ __forceinline__ float cos_rev(float u){ float r; asm("v_cos_f32 %0, %1" : "=v"(r) : "v"(u)); return r; }
__device__ __forceinline__ unsigned int cvt_pk(float lo, float hi){
    unsigned int r; asm("v_cvt_pk_bf16_f32 %0, %1, %2" : "=v"(r) : "v"(lo), "v"(hi)); return r;
}
__device__ __forceinline__ s16x8 bneg(s16x8 v){
    int4 u = *(int4*)&v;
    u.x ^= 0x80008000; u.y ^= 0x80008000; u.z ^= 0x80008000; u.w ^= 0x80008000;
    return *(s16x8*)&u;
}
// swizzled byte offset of 16B granule (row,kg) in a [64][32]-ushort plane (64B rows).
__device__ __forceinline__ int swz(int row, int kg){
    return row*64 + ((kg ^ ((row>>1)&3))<<4);
}

// ---- pre-pass: cg fp32 -> bf16 in 32x32x16 MFMA-fragment order ----
// chunk c = wm*4 + mp*2 + kh; 16B chunk gid = ((tile*2+plane)*8 + c)*64 + lane
// content = bf16(cg[wm*64 + mp*32 + (lane&31)][tile*32 + kh*16 + (lane>>5)*8 ..+8])
__global__ __launch_bounds__(256) void bloch_prepass(
    const float* __restrict__ cgr, const float* __restrict__ cgi,
    char* __restrict__ ws)
{
    int gid = blockIdx.x*256 + threadIdx.x;
    if (gid >= NKC*NTILES*2*8*64) return;
    int lane  = gid & 63;
    int c     = (gid >> 6) & 7;
    int plane = (gid >> 9) & 1;
    int tile  = gid >> 10;
    int wm = c >> 2, mp = (c >> 1) & 1, kh = c & 1;
    int row = wm*64 + mp*32 + (lane & 31);
    int k   = tile*32 + kh*16 + (lane >> 5)*8;
    const float* src = plane ? cgi : cgr;
    const float4 v0 = *(const float4*)&src[(size_t)row*NG + k];
    const float4 v1 = *(const float4*)&src[(size_t)row*NG + k + 4];
    uint4 p;
    p.x = cvt_pk(v0.x, v0.y); p.y = cvt_pk(v0.z, v0.w);
    p.z = cvt_pk(v1.x, v1.y); p.w = cvt_pk(v1.z, v1.w);
    *(uint4*)(ws + (size_t)gid*16) = p;
}

// R13 structure + 32x32x16 MFMA (8.07 cyc/CU for 2x FLOP of 16x16x32 at 4.85
// -> 1.21x efficiency, floor 31.6 -> 26.3 us; half the issue slots).
// (256,2): cap 256 VGPR, no spill (R8 lesson). Staging/ring proven in R13.
template<bool PRE>
__global__ __launch_bounds__(TPB, 2) void bloch16(
    const float* __restrict__ Amat, const float* __restrict__ kgrid,
    const float* __restrict__ cgr,  const float* __restrict__ cgi,
    const float* __restrict__ rpts, const char* __restrict__ ws,
    float* __restrict__ out, int out_size)
{
    // B ring: 6 slots x (Bc 4K | Bs 4K) = 48KB (192 g). Disjointness proven (R13).
    __shared__ __align__(16) char smem[NSLOT*8192];
    __shared__ float fracS[NT][4];
    __shared__ float invAS[9];
    __shared__ float scaleS;

    const int tid = threadIdx.x;
    const int bid = blockIdx.x;
    const int kc  = bid >> 7;           // 0..9
    const int rb  = bid & 127;          // 0..127
    if (rb >= 125) return;              // uniform early-out
    const int r_base = rb * NT;

    if (tid == 0) {
        float a00=Amat[0],a01=Amat[1],a02=Amat[2];
        float a10=Amat[3],a11=Amat[4],a12=Amat[5];
        float a20=Amat[6],a21=Amat[7],a22=Amat[8];
        float c00 =  (a11*a22 - a12*a21);
        float c01 = -(a10*a22 - a12*a20);
        float c02 =  (a10*a21 - a11*a20);
        float det = a00*c00 + a01*c01 + a02*c02;
        float id  = 1.0f/det;
        invAS[0] =  c00*id;
        invAS[1] = -(a01*a22 - a02*a21)*id;
        invAS[2] =  (a01*a12 - a02*a11)*id;
        invAS[3] =  c01*id;
        invAS[4] =  (a00*a22 - a02*a20)*id;
        invAS[5] = -(a00*a12 - a02*a10)*id;
        invAS[6] =  c02*id;
        invAS[7] = -(a00*a21 - a01*a20)*id;
        invAS[8] =  (a00*a11 - a01*a10)*id;
        scaleS   = rsqrtf(fabsf(det));
    }
    __syncthreads();

    if (tid < NT) {
        int rg = r_base + tid;
        float r0 = rpts[rg*3+0], r1 = rpts[rg*3+1], r2 = rpts[rg*3+2];
        fracS[tid][0] = r0*invAS[0] + r1*invAS[3] + r2*invAS[6];
        fracS[tid][1] = r0*invAS[1] + r1*invAS[4] + r2*invAS[7];
        fracS[tid][2] = r0*invAS[2] + r1*invAS[5] + r2*invAS[8];
    }
    __syncthreads();

    f32x16 accRe[2], accIm[2];          // [mp]: 2x (Re,Im) 32x32 tiles = 64 regs
    #pragma unroll
    for (int mp = 0; mp < 2; ++mp) {
        #pragma unroll
        for (int e = 0; e < 16; ++e) { accRe[mp][e] = 0.f; accIm[mp][e] = 0.f; }
    }

    const int lane = tid & 63;
    const int wid  = tid >> 6;     // 0..3
    const int wm   = wid >> 1;     // M half (64 rows)
    const int wn   = wid & 1;      // N half (32 cols)
    const int colL = wn*32 + (lane & 31);
    const int hB   = lane >> 5;    // k-subgroup 0..1

    // B-frag read offsets: granule = kh*2 + hB
    const int bOff0 = swz(colL, 0*2 + hB);
    const int bOff1 = swz(colL, 1*2 + hB);

    // staging: row = lane, run index = wid (wave-uniform store paths)
    const float f0r = fracS[lane][0], f1r = fracS[lane][1], f2r = fracS[lane][2];
    float u1 = f2r - floorf(f2r);
    const float w1c = cos_rev(u1), w1s = sin_rev(u1);        // e^{2pi i f2}
    float yd = -20.0f * f2r; yd -= floorf(yd);
    const float wdc = cos_rev(yd), wds = sin_rev(yd);
    const float w1wdc = w1c*wdc - w1s*wds;                   // w1 * e^{-2pi i 20 f2}
    const float w1wds = w1c*wds + w1s*wdc;

    // stage round R: 20-aligned run per thread (proven in R13)
    auto stageRing = [&](int R){
        int i12 = kc*40 + 4*R + wid;
        int i1  = (i12 * 3277) >> 16;
        int i2  = i12 - i1*20;
        float m1 = (float)(i1 - (i1 >= 10 ? 20 : 0));
        float m2 = (float)(i2 - (i2 >= 10 ? 20 : 0));
        float y0 = m1*f0r + m2*f1r; y0 -= floorf(y0);
        float cc = cos_rev(y0), cs = sin_rev(y0);
        unsigned int pkc[10], pks[10];
        #pragma unroll
        for (int jj = 0; jj < 10; ++jj) {
            float ac = cc, as_ = cs;
            { float nc = cc*w1c - cs*w1s, ns = cc*w1s + cs*w1c; cc=nc; cs=ns; }
            pkc[jj] = cvt_pk(ac, cc);
            pks[jj] = cvt_pk(as_, cs);
            if (jj < 9) {
                if (jj == 4) { float nc = cc*w1wdc - cs*w1wds, ns = cc*w1wds + cs*w1wdc; cc=nc; cs=ns; }
                else         { float nc = cc*w1c  - cs*w1s,  ns = cc*w1s  + cs*w1c;  cc=nc; cs=ns; }
            }
        }
        int gg = (80*R + wid*20) % 192;
        int gA = gg >> 3;
        auto adr = [&](int g, int p)->char* {
            if (g >= 24) g -= 24;
            return smem + (g>>2)*8192 + p*4096 + swz(lane, g&3);
        };
        if ((gg & 7) == 0) {
            *(uint4*)adr(gA,0)   = make_uint4(pkc[0],pkc[1],pkc[2],pkc[3]);
            *(uint4*)adr(gA+1,0) = make_uint4(pkc[4],pkc[5],pkc[6],pkc[7]);
            *(uint2*)adr(gA+2,0) = make_uint2(pkc[8],pkc[9]);
            *(uint4*)adr(gA,1)   = make_uint4(pks[0],pks[1],pks[2],pks[3]);
            *(uint4*)adr(gA+1,1) = make_uint4(pks[4],pks[5],pks[6],pks[7]);
            *(uint2*)adr(gA+2,1) = make_uint2(pks[8],pks[9]);
        } else {
            *(uint2*)(adr(gA,0)+8) = make_uint2(pkc[0],pkc[1]);
            *(uint4*)adr(gA+1,0)   = make_uint4(pkc[2],pkc[3],pkc[4],pkc[5]);
            *(uint4*)adr(gA+2,0)   = make_uint4(pkc[6],pkc[7],pkc[8],pkc[9]);
            *(uint2*)(adr(gA,1)+8) = make_uint2(pks[0],pks[1]);
            *(uint4*)adr(gA+1,1)   = make_uint4(pks[2],pks[3],pks[4],pks[5]);
            *(uint4*)adr(gA+2,1)   = make_uint4(pks[6],pks[7],pks[8],pks[9]);
        }
    };

    s16x8 arf[2][2], aif[2][2];    // [mp][kh] A fragments (current tile)
    auto loadA = [&](int t){
        const char* tb = ws + (size_t)(kc*NTILES + t)*WS_TILE_B + lane*16;
        #pragma unroll
        for (int mp = 0; mp < 2; ++mp)
            #pragma unroll
            for (int kh = 0; kh < 2; ++kh) {
                arf[mp][kh] = *(const s16x8*)(tb +        (wm*4 + mp*2 + kh)*1024);
                aif[mp][kh] = *(const s16x8*)(tb + 8192 + (wm*4 + mp*2 + kh)*1024);
            }
    };
    auto loadA_direct = [&](int t){
        #pragma unroll
        for (int mp = 0; mp < 2; ++mp)
            #pragma unroll
            for (int kh = 0; kh < 2; ++kh) {
                int row = wm*64 + mp*32 + (lane & 31);
                int k   = kc*KCH + t*32 + kh*16 + hB*8;
                const float* pr_ = &cgr[(size_t)row*NG + k];
                const float* pi_ = &cgi[(size_t)row*NG + k];
                float4 r0 = *(const float4*)pr_, r1 = *(const float4*)(pr_+4);
                float4 i0 = *(const float4*)pi_, i1 = *(const float4*)(pi_+4);
                union { s16x8 v; uint4 u; } pr, pi;
                pr.u = make_uint4(cvt_pk(r0.x,r0.y), cvt_pk(r0.z,r0.w),
                                  cvt_pk(r1.x,r1.y), cvt_pk(r1.z,r1.w));
                pi.u = make_uint4(cvt_pk(i0.x,i0.y), cvt_pk(i0.z,i0.w),
                                  cvt_pk(i1.x,i1.y), cvt_pk(i1.z,i1.w));
                arf[mp][kh] = pr.v; aif[mp][kh] = pi.v;
            }
    };

    // prologue
    if (PRE) loadA(0); else loadA_direct(0);
    stageRing(0);
    __syncthreads();

    int tcur = 0, slot = 0;
    #pragma unroll 1
    for (int R = 0; R < NROUND; ++R) {
        if (R + 1 < NROUND) stageRing(R + 1);
        const int t_hi = (5*R + 5) >> 1;
        #pragma unroll 1
        while (tcur < t_hi) {
            const char* base = smem + slot*8192;
            s16x8 bcf[2], bsf[2], bsnf[2];
            bcf[0] = *(const s16x8*)(base +        bOff0);
            bcf[1] = *(const s16x8*)(base +        bOff1);
            bsf[0] = *(const s16x8*)(base + 4096 + bOff0);
            bsf[1] = *(const s16x8*)(base + 4096 + bOff1);
            bsnf[0] = bneg(bsf[0]); bsnf[1] = bneg(bsf[1]);
            __builtin_amdgcn_s_setprio(1);
            #pragma unroll
            for (int kh = 0; kh < 2; ++kh) {
                // same-acc dependency spacing = 4 MFMAs
                accRe[0] = __builtin_amdgcn_mfma_f32_32x32x16_bf16(arf[0][kh], bcf[kh],  accRe[0], 0, 0, 0);
                accRe[1] = __builtin_amdgcn_mfma_f32_32x32x16_bf16(arf[1][kh], bcf[kh],  accRe[1], 0, 0, 0);
                accIm[0] = __builtin_amdgcn_mfma_f32_32x32x16_bf16(arf[0][kh], bsf[kh],  accIm[0], 0, 0, 0);
                accIm[1] = __builtin_amdgcn_mfma_f32_32x32x16_bf16(arf[1][kh], bsf[kh],  accIm[1], 0, 0, 0);
                accRe[0] = __builtin_amdgcn_mfma_f32_32x32x16_bf16(aif[0][kh], bsnf[kh], accRe[0], 0, 0, 0);
                accRe[1] = __builtin_amdgcn_mfma_f32_32x32x16_bf16(aif[1][kh], bsnf[kh], accRe[1], 0, 0, 0);
                accIm[0] = __builtin_amdgcn_mfma_f32_32x32x16_bf16(aif[0][kh], bcf[kh],  accIm[0], 0, 0, 0);
                accIm[1] = __builtin_amdgcn_mfma_f32_32x32x16_bf16(aif[1][kh], bcf[kh],  accIm[1], 0, 0, 0);
            }
            __builtin_amdgcn_s_setprio(0);
            ++tcur;
            if (tcur < NTILES) { if (PRE) loadA(tcur); else loadA_direct(tcur); }
            ++slot; if (slot == NSLOT) slot = 0;
        }
        __syncthreads();
    }

    // ---- e^{i k.r} table overlay on smem; one sincos per thread ----
    float2* ekr = (float2*)smem;   // [64][4]
    {
        int col = tid >> 2, kidx = tid & 3;
        int rg = r_base + col;
        float r0 = rpts[rg*3+0], r1 = rpts[rg*3+1], r2 = rpts[rg*3+2];
        float ang = (r0*kgrid[kidx*3+0] + r1*kgrid[kidx*3+1] + r2*kgrid[kidx*3+2])
                    * 0.15915494309189535f;
        float u = ang - floorf(ang);
        ekr[col*4+kidx] = make_float2(cos_rev(u), sin_rev(u));
    }
    __syncthreads();

    // ---- epilogue: C/D layout col=lane&31, row=(reg&3)+8*(reg>>2)+4*(lane>>5) ----
    const bool write_imag = (out_size >= 2*NSKIN*NRPT);
    const float scale = scaleS;
    const int rg = r_base + colL;
    #pragma unroll
    for (int mp = 0; mp < 2; ++mp) {
        #pragma unroll
        for (int q = 0; q < 4; ++q) {
            const int kidx = mp*2 + (q >> 1);
            float2 e = ekr[colL*4 + kidx];
            float ck = e.x, sk = e.y;
            #pragma unroll
            for (int rr = 0; rr < 4; ++rr) {
                const int reg = q*4 + rr;
                int row = rr + 8*q + 4*hB;
                int sg  = wm*64 + mp*32 + row;
                float re = accRe[mp][reg];
                float im = accIm[mp][reg];
                float orr = (re*ck - im*sk) * scale;
                size_t lin = (size_t)sg * NRPT + rg;
                if (write_imag) {
                    float oi = (re*sk + im*ck) * scale;
                    size_t idx2 = lin * 2;
                    if (idx2 + 1 < (size_t)out_size) {
                        atomicAdd(&out[idx2],   orr);
                        atomicAdd(&out[idx2+1], oi);
                    }
                } else {
                    atomicAdd(&out[lin], orr);
                }
            }
        }
    }
}

extern "C" void kernel_launch(void* const* d_in, const int* in_sizes, int n_in,
                              void* d_out, int out_size, void* d_ws, size_t ws_size,
                              hipStream_t stream) {
    const float* Amat  = (const float*)d_in[0];
    const float* kgrid = (const float*)d_in[1];
    const float* cgr   = (const float*)d_in[2];
    const float* cgi   = (const float*)d_in[3];
    const float* rpts  = (const float*)d_in[4];
    float* out = (float*)d_out;

    hipMemsetAsync(d_out, 0, (size_t)out_size * sizeof(float), stream);

    const bool use_pre = (ws_size >= WS_NEED);
    dim3 grid(NKC * 128);   // kc = bid>>7, rb = bid&127 (3 dead bids per kc)
    if (use_pre) {
        bloch_prepass<<<dim3(NKC*NTILES*2*8*64/256), 256, 0, stream>>>(cgr, cgi, (char*)d_ws);
        bloch16<true><<<grid, TPB, 0, stream>>>(Amat, kgrid, cgr, cgi, rpts,
                                                (const char*)d_ws, out, out_size);
    } else {
        bloch16<false><<<grid, TPB, 0, stream>>>(Amat, kgrid, cgr, cgi, rpts,
                                                 nullptr, out, out_size);
    }
}